// Round 14
// baseline (76.697 us; speedup 1.0000x reference)
//
#include <hip/hip_runtime.h>

#define T 16
#define E 30
#define H 50
#define VOCAB 100
#define ROWS 208        // 13 tiles of 16 rows
#define K1 1.44269504089f   // log2(e)
#define K2 2.88539008178f   // 2*log2(e)
#define NTILE 13
#define TSTRIDE 210     // halves per vocab row in LDS (208+2 pad; odd word stride)

typedef _Float16 v8hf __attribute__((ext_vector_type(8)));
typedef _Float16 v4hf __attribute__((ext_vector_type(4)));
typedef float v4f __attribute__((ext_vector_type(4)));

extern "C" __device__ float __ocml_native_exp2_f32(float);
__device__ __forceinline__ float e2(float x)   { return __ocml_native_exp2_f32(x); }
__device__ __forceinline__ float rcpf(float x) { return __builtin_amdgcn_rcpf(x); }

// Lane-local unit assignment: tile i, row-group lgc, gate g <-> unit u = lgc*13+i.
// tbl row r = 16*tile + rho, rho = lgc*4 + gate. Pre-scaled by -log2e (i,f,o) / 2log2e (g).
__global__ void build_tbl(const float* __restrict__ emb,
                          const float* __restrict__ w_ih,
                          const float* __restrict__ b_ih,
                          const float* __restrict__ b_hh,
                          float* __restrict__ tbl) {
    int idx = blockIdx.x * blockDim.x + threadIdx.x;
    if (idx >= VOCAB * ROWS) return;
    int v = idx / ROWS, r = idx % ROWS;
    int tile = r >> 4, rho = r & 15;
    int lgc = rho >> 2, gate = rho & 3;
    int u = lgc * 13 + tile;
    float s = 0.f;
    if (u < H) {
        int orig = gate * H + u;
        s = b_ih[orig] + b_hh[orig];
        const float* er = emb + v * E;
        const float* wr = w_ih + orig * E;
#pragma unroll
        for (int e = 0; e < E; ++e) s += er[e] * wr[e];
        s *= (gate == 2) ? K2 : -K1;
    }
    tbl[idx] = s;
}

// Zero-LDS recurrence (h stays in registers, R12) + LDS-resident fp16 gate
// table: kills the 106 KB/CU/step L1-miss gather that R9-R13 stalled on.
__global__ __launch_bounds__(256, 2) void lstm_mfma(
    const int* __restrict__ ids,     // [NSEQ, T]
    const float* __restrict__ tbl,   // [2][VOCAB][ROWS] f32
    const float* __restrict__ whh_f, // [200][50]
    const float* __restrict__ whh_r, // [200][50]
    float* __restrict__ out)         // [NSEQ, 100]
{
    __shared__ _Float16 tl[VOCAB * TSTRIDE];   // 42 KB, this block's direction

    const int tid = threadIdx.x;
    const int lane = tid & 63;
    const int wave = tid >> 6;
    const int l15 = lane & 15;       // seq within wave / C col
    const int lg = lane >> 4;        // k-/B-slot group
    const int b = blockIdx.x;
    const int dir = b >> 8;          // 512 blocks: 0..255 fwd, 256..511 rev
    const int seq = (b & 255) * 64 + wave * 16 + l15;

    const float* __restrict__ whh = dir ? whh_r : whh_f;
    const float* __restrict__ tb  = tbl + dir * (VOCAB * ROWS);
    const int* __restrict__ myids = ids + seq * T;

    // ---- stage this direction's table into LDS as fp16 ----
    for (int idx = tid; idx < VOCAB * ROWS; idx += 256) {
        int v = idx / ROWS, r = idx - v * ROWS;
        tl[v * TSTRIDE + r] = (_Float16)tb[idx];
    }

    // ragged length -> capture step (per lane's own sequence)
    int capt;
    {
        const int4* q = (const int4*)myids;
        int4 a0 = q[0], a1 = q[1], a2 = q[2], a3 = q[3];
        int len = (a0.x != 0) + (a0.y != 0) + (a0.z != 0) + (a0.w != 0)
                + (a1.x != 0) + (a1.y != 0) + (a1.z != 0) + (a1.w != 0)
                + (a2.x != 0) + (a2.y != 0) + (a2.z != 0) + (a2.w != 0)
                + (a3.x != 0) + (a3.y != 0) + (a3.z != 0) + (a3.w != 0);
        capt = dir ? (T - 1) : ((len > 1) ? (len - 1) : 0);
    }

    // A-fragments: lane(lg,l15) tile i kh: af[j] = A[16i+l15][kh*32+lg*8+j]
    //   row: gate = l15&3 of unit urow = (l15>>2)*13 + i
    //   col k-slot (kh,lg,j): unit ucol = lg*13 + kh*8 + j (zero if pad)
    const int gate = l15 & 3;
    const int rbase = (l15 >> 2) * 13;
    const float sc = (gate == 2) ? K2 : -K1;
    v8hf afrag[NTILE][2];
#pragma unroll
    for (int i = 0; i < NTILE; ++i) {
        const int urow = rbase + i;
        const bool vrow = (urow < H);
        const int worow = (gate * H + (vrow ? urow : 0)) * H;
#pragma unroll
        for (int kh = 0; kh < 2; ++kh) {
            v8hf af;
#pragma unroll
            for (int j = 0; j < 8; ++j) {
                const int m = kh * 8 + j;
                const int ucol = lg * 13 + m;
                const bool vcol = (m < NTILE) && (ucol < H);
                af[j] = (_Float16)((vrow && vcol) ? sc * whh[worow + ucol] : 0.f);
            }
            afrag[i][kh] = af;
        }
    }

    __syncthreads();   // tl staged (afrag loads overlapped the LDS writes)

    float cs[NTILE];
#pragma unroll
    for (int i = 0; i < NTILE; ++i) cs[i] = 0.f;

    v8hf b0 = (v8hf)(_Float16)0.f;   // h(t-1) units lg*13+0..7   (t=0: zeros)
    v8hf b1 = (v8hf)(_Float16)0.f;   // h(t-1) units lg*13+8..12 + pads

    int id_next = myids[dir ? (T - 1) : 0];

#pragma unroll 1   // rolled t-loop
    for (int t = 0; t < T; ++t) {
        const int id = id_next;
        int tn = dir ? (T - 2 - t) : (t + 1);
        if (t == T - 1) tn = dir ? 0 : (T - 1);    // dummy valid index
        id_next = myids[tn];

        const _Float16* __restrict__ trow = tl + id * TSTRIDE + lg * 4;
        const bool cap = (t == capt);

        v8hf nb0;
        v8hf nb1 = (v8hf)(_Float16)0.f;

#pragma unroll
        for (int i = 0; i < NTILE; ++i) {
            // gate-table C init from LDS (fp16 -> f32)
            v4hf th = *(const v4hf*)(trow + i * 16);
            v4f tvv;
            tvv[0] = (float)th[0]; tvv[1] = (float)th[1];
            tvv[2] = (float)th[2]; tvv[3] = (float)th[3];

            v4f c = __builtin_amdgcn_mfma_f32_16x16x32_f16(afrag[i][0], b0, tvv, 0, 0, 0);
            c = __builtin_amdgcn_mfma_f32_16x16x32_f16(afrag[i][1], b1, c, 0, 0, 0);

            // combined-denominator LSTM update: 5 exp2 + 2 rcp per unit
            float ei = e2(c[0]);
            float ef = e2(c[1]);
            float eg = e2(c[2]);
            float eo = e2(c[3]);
            float ai  = 1.f + ei;
            float bf  = 1.f + ef;
            float gp  = eg + 1.f;
            float gm2 = fmaf(K2, eg, -K2);            // K2*(eg-1)
            float num = fmaf(cs[i] * ai, gp, gm2 * bf);
            float rD  = rcpf(ai * bf * gp);
            float cn  = num * rD;                      // cs' = K2 * c_new
            cs[i] = cn;
            float ec  = e2(cn);                        // e^(2 c_new)
            float h   = (ec - 1.f) * rcpf((1.f + eo) * (ec + 1.f));

            if (i < 8) nb0[i] = (_Float16)h;
            else       nb1[i - 8] = (_Float16)h;
            if (cap && (i < 11 || lg < 3))
                out[seq * 100 + dir * H + lg * NTILE + i] = h;
        }
        b0 = nb0; b1 = nb1;
    }
}

extern "C" void kernel_launch(void* const* d_in, const int* in_sizes, int n_in,
                              void* d_out, int out_size, void* d_ws, size_t ws_size,
                              hipStream_t stream) {
    const int*   char_ids = (const int*)d_in[0];
    const float* emb      = (const float*)d_in[1];
    const float* w_ih_f   = (const float*)d_in[2];
    const float* w_hh_f   = (const float*)d_in[3];
    const float* b_ih_f   = (const float*)d_in[4];
    const float* b_hh_f   = (const float*)d_in[5];
    const float* w_ih_r   = (const float*)d_in[6];
    const float* w_hh_r   = (const float*)d_in[7];
    const float* b_ih_r   = (const float*)d_in[8];
    const float* b_hh_r   = (const float*)d_in[9];
    float* out = (float*)d_out;
    float* tbl = (float*)d_ws; // [2][VOCAB][ROWS] f32 = 166.4 KB

    const int nt = VOCAB * ROWS; // 20800
    build_tbl<<<(nt + 255) / 256, 256, 0, stream>>>(emb, w_ih_f, b_ih_f, b_hh_f, tbl);
    build_tbl<<<(nt + 255) / 256, 256, 0, stream>>>(emb, w_ih_r, b_ih_r, b_hh_r, tbl + nt);
    // 512 blocks x 256: 4 independent 16-seq waves per block; table in LDS
    lstm_mfma<<<512, 256, 0, stream>>>(char_ids, tbl, w_hh_f, w_hh_r, out);
}

// Round 15
// 70.398 us; speedup vs baseline: 1.0895x; 1.0895x over previous
//
#include <hip/hip_runtime.h>

#define T 16
#define E 30
#define H 50
#define VOCAB 100
#define ROWS 208        // 13 row-tiles of 16; rows interleaved r = 4*unit + gate
#define K1 1.44269504089f   // log2(e)
#define K2 2.88539008178f   // 2*log2(e)

typedef _Float16 v8hf __attribute__((ext_vector_type(8)));
typedef float v4f __attribute__((ext_vector_type(4)));

extern "C" __device__ float __ocml_native_exp2_f32(float);
__device__ __forceinline__ float e2(float x)   { return __ocml_native_exp2_f32(x); }
__device__ __forceinline__ float rcpf(float x) { return __builtin_amdgcn_rcpf(x); }

// tbl[dir][v][r], r = 4*unit + gate (i,f,g,o), orig row = gate*50+unit.
// Pre-scaled: i/f/o rows by -log2e, g rows by 2*log2e.
__global__ void build_tbl(const float* __restrict__ emb,
                          const float* __restrict__ w_ih,
                          const float* __restrict__ b_ih,
                          const float* __restrict__ b_hh,
                          float* __restrict__ tbl) {
    int idx = blockIdx.x * blockDim.x + threadIdx.x;
    if (idx >= VOCAB * ROWS) return;
    int v = idx / ROWS, r = idx % ROWS;
    float s = 0.f;
    if (r < 4 * H) {
        int orig = (r & 3) * H + (r >> 2);
        s = b_ih[orig] + b_hh[orig];
        const float* er = emb + v * E;
        const float* wr = w_ih + orig * E;
#pragma unroll
        for (int e = 0; e < E; ++e) s += er[e] * wr[e];
        s *= ((r & 3) == 2) ? K2 : -K1;
    }
    tbl[idx] = s;
}

// M-split: 2 waves share a 16-seq group (tiles 0-6 / 7-12), exchanging h via
// a reader-packed LDS buffer, double-buffered by step parity. Sync = raw
// s_barrier + lgkmcnt(0) only (tv global prefetches stay in flight across it).
// 4096 waves = 4/SIMD — double the TLP of R9-R14's plateau structures.
// hbuf entry [kh][lane][j] = h[seq=lane&15][unit kh*32 + (lane>>4)*8 + j].
template<int RT0, int NT>
__device__ __forceinline__ void run_tiles(
    const float* __restrict__ whh, const float* __restrict__ tb,
    const int* __restrict__ myids, _Float16* __restrict__ hb,
    float* __restrict__ out, int seq, int dir, int capt, int lane)
{
    const int l15 = lane & 15;
    const int lg = lane >> 4;

    // A-fragments (pre-scaled fp16 W) resident for the whole kernel (~56 VGPR)
    v8hf afrag[NT][2];
#pragma unroll
    for (int i = 0; i < NT; ++i) {
        const int r = (RT0 + i) * 16 + l15;
        const bool vr = (r < 4 * H);
        const int orig = vr ? ((r & 3) * H + (r >> 2)) : 0;
        const float sc = ((r & 3) == 2) ? K2 : -K1;
#pragma unroll
        for (int kh = 0; kh < 2; ++kh) {
            v8hf af;
#pragma unroll
            for (int j = 0; j < 8; ++j) {
                const int k = kh * 32 + lg * 8 + j;
                af[j] = (_Float16)((vr && k < H) ? sc * whh[orig * H + k] : 0.f);
            }
            afrag[i][kh] = af;
        }
    }

    // h write offsets (halves): unit u=(RT0+i)*4+lg -> [u>>5][((u&31)>>3)*16+l15][u&7]
    unsigned wa[NT];
#pragma unroll
    for (int i = 0; i < NT; ++i) {
        const int u = (RT0 + i) * 4 + lg;
        wa[i] = ((u >> 5) << 9) + (((u & 31) >> 3) << 7) + (l15 << 3) + (u & 7);
    }

    float cs[NT];
#pragma unroll
    for (int i = 0; i < NT; ++i) cs[i] = 0.f;

    // prefetch tv for t=0
    v4f tv[NT];
    {
        const int id0 = myids[dir ? (T - 1) : 0];
        const float* __restrict__ trow = tb + id0 * ROWS;
#pragma unroll
        for (int i = 0; i < NT; ++i)
            tv[i] = *(const v4f*)(trow + (RT0 + i) * 16 + lg * 4);
    }

#pragma unroll 1
    for (int t = 0; t < T; ++t) {
        const int cur = t & 1, nxt = cur ^ 1;
        int tn = dir ? (T - 2 - t) : (t + 1);
        if (t == T - 1) tn = dir ? 0 : (T - 1);    // dummy valid index
        const int id_next = myids[tn];
        const float* __restrict__ trow_n = tb + id_next * ROWS;

        // full previous-step h: conflict-free contiguous b128 reads
        v8hf bh0 = *(const v8hf*)(hb + cur * 1024 + lane * 8);
        v8hf bh1 = *(const v8hf*)(hb + cur * 1024 + 512 + lane * 8);

        _Float16* wb = hb + nxt * 1024;
        const bool cap = (t == capt);

#pragma unroll
        for (int i = 0; i < NT; ++i) {
            v4f c = __builtin_amdgcn_mfma_f32_16x16x32_f16(afrag[i][0], bh0, tv[i], 0, 0, 0);
            c = __builtin_amdgcn_mfma_f32_16x16x32_f16(afrag[i][1], bh1, c, 0, 0, 0);
            tv[i] = *(const v4f*)(trow_n + (RT0 + i) * 16 + lg * 4);   // prefetch t+1

            // combined-denominator LSTM update: 5 exp2 + 2 rcp per unit
            float ei = e2(c[0]);
            float ef = e2(c[1]);
            float eg = e2(c[2]);
            float eo = e2(c[3]);
            float ai  = 1.f + ei;
            float bf  = 1.f + ef;
            float gp  = eg + 1.f;
            float gm2 = fmaf(K2, eg, -K2);            // K2*(eg-1)
            float num = fmaf(cs[i] * ai, gp, gm2 * bf);
            float rD  = rcpf(ai * bf * gp);
            float cn  = num * rD;                      // cs' = K2 * c_new
            cs[i] = cn;
            float ec  = e2(cn);                        // e^(2 c_new)
            float hn  = (ec - 1.f) * rcpf((1.f + eo) * (ec + 1.f));

            if (RT0 + i < 12 || lg < 2) {              // unit u < 50
                wb[wa[i]] = (_Float16)hn;
                if (cap) out[seq * 100 + dir * H + (RT0 + i) * 4 + lg] = hn;
            }
        }

        // drain LDS only, raw barrier: global prefetches stay in flight
        asm volatile("s_waitcnt lgkmcnt(0)" ::: "memory");
        __builtin_amdgcn_s_barrier();
        asm volatile("" ::: "memory");
    }
}

__global__ __launch_bounds__(256, 4) void lstm_mfma(
    const int* __restrict__ ids,     // [NSEQ, T]
    const float* __restrict__ tbl,   // [2][VOCAB][ROWS]
    const float* __restrict__ whh_f, // [200][50]
    const float* __restrict__ whh_r, // [200][50]
    float* __restrict__ out)         // [NSEQ, 100]
{
    // [grp][buf][seg][lane][8] fp16 = 8 KB
    __shared__ _Float16 hbuf[2][2][2][64][8];

    const int tid = threadIdx.x;
    const int lane = tid & 63;
    const int wv = tid >> 6;
    const int grp = wv >> 1;         // 2 independent 16-seq groups per block
    const int halfM = wv & 1;        // M-split: tiles 0-6 / 7-12
    const int l15 = lane & 15;
    const int b = blockIdx.x;
    const int dir = b >> 9;          // 1024 blocks: 0..511 fwd, 512..1023 rev
    const int seq = (b & 511) * 32 + grp * 16 + l15;

    const float* __restrict__ whh = dir ? whh_r : whh_f;
    const float* __restrict__ tb  = tbl + dir * (VOCAB * ROWS);
    const int* __restrict__ myids = ids + seq * T;

    // zero all h buffers (4096 halves = 2048 ints; pads stay zero forever)
    {
        int* hz = (int*)&hbuf[0][0][0][0][0];
#pragma unroll
        for (int i = tid; i < 2048; i += 256) hz[i] = 0;
    }

    // ragged length -> capture step (per lane's own sequence)
    int capt;
    {
        const int4* q = (const int4*)myids;
        int4 a0 = q[0], a1 = q[1], a2 = q[2], a3 = q[3];
        int len = (a0.x != 0) + (a0.y != 0) + (a0.z != 0) + (a0.w != 0)
                + (a1.x != 0) + (a1.y != 0) + (a1.z != 0) + (a1.w != 0)
                + (a2.x != 0) + (a2.y != 0) + (a2.z != 0) + (a2.w != 0)
                + (a3.x != 0) + (a3.y != 0) + (a3.z != 0) + (a3.w != 0);
        capt = dir ? (T - 1) : ((len > 1) ? (len - 1) : 0);
    }

    __syncthreads();   // hbuf zeroed (full sync once, pre-loop)

    _Float16* hb = &hbuf[grp][0][0][0][0];
    if (halfM == 0) run_tiles<0, 7>(whh, tb, myids, hb, out, seq, dir, capt, lane);
    else            run_tiles<7, 6>(whh, tb, myids, hb, out, seq, dir, capt, lane);
}

extern "C" void kernel_launch(void* const* d_in, const int* in_sizes, int n_in,
                              void* d_out, int out_size, void* d_ws, size_t ws_size,
                              hipStream_t stream) {
    const int*   char_ids = (const int*)d_in[0];
    const float* emb      = (const float*)d_in[1];
    const float* w_ih_f   = (const float*)d_in[2];
    const float* w_hh_f   = (const float*)d_in[3];
    const float* b_ih_f   = (const float*)d_in[4];
    const float* b_hh_f   = (const float*)d_in[5];
    const float* w_ih_r   = (const float*)d_in[6];
    const float* w_hh_r   = (const float*)d_in[7];
    const float* b_ih_r   = (const float*)d_in[8];
    const float* b_hh_r   = (const float*)d_in[9];
    float* out = (float*)d_out;
    float* tbl = (float*)d_ws; // [2][VOCAB][ROWS] f32 = 166.4 KB

    const int nt = VOCAB * ROWS; // 20800
    build_tbl<<<(nt + 255) / 256, 256, 0, stream>>>(emb, w_ih_f, b_ih_f, b_hh_f, tbl);
    build_tbl<<<(nt + 255) / 256, 256, 0, stream>>>(emb, w_ih_r, b_ih_r, b_hh_r, tbl + nt);
    // 1024 blocks x 256: 2 seq-groups x 2 M-split waves -> 4096 waves (4/SIMD)
    lstm_mfma<<<1024, 256, 0, stream>>>(char_ids, tbl, w_hh_f, w_hh_r, out);
}